// Round 1
// baseline (1083.682 us; speedup 1.0000x reference)
//
#include <hip/hip_runtime.h>
#include <hip/hip_bf16.h>

#define E_    8
#define T_    4096
#define D_    2048
#define HDIM  1024

typedef __bf16 bf16_t;
typedef __bf16 bf16x8 __attribute__((ext_vector_type(8)));
typedef __bf16 bf16x4 __attribute__((ext_vector_type(4)));
typedef float  floatx4 __attribute__((ext_vector_type(4)));

// ---------------- prep kernels ----------------

// fp32 -> bf16, 4 elements/thread (float4 load, 8B store)
__global__ void cvt_f32_bf16(const float* __restrict__ in, bf16_t* __restrict__ out, long n4) {
  long i = (long)blockIdx.x * blockDim.x + threadIdx.x;
  if (i >= n4) return;
  const float4 v = ((const float4*)in)[i];
  bf16x4 o;
  o[0] = (bf16_t)v.x; o[1] = (bf16_t)v.y; o[2] = (bf16_t)v.z; o[3] = (bf16_t)v.w;
  ((bf16x4*)out)[i] = o;
}

// in: R x C fp32 row-major (per expert), out: C x R bf16 row-major (per expert)
__global__ void transpose_cvt(const float* __restrict__ in, bf16_t* __restrict__ out,
                              int R, int C, long sIn, long sOut) {
  __shared__ float t[32][33];   // +1 pad: no bank conflicts
  const float* inE = in + (long)blockIdx.z * sIn;
  bf16_t* outE = out + (long)blockIdx.z * sOut;
  const int tx = threadIdx.x & 31;
  const int ty = threadIdx.x >> 5;     // 0..7
  const int c0 = blockIdx.x * 32;
  const int r0 = blockIdx.y * 32;
#pragma unroll
  for (int j = 0; j < 4; ++j) {
    int r = ty + j * 8;
    t[r][tx] = inE[(long)(r0 + r) * C + c0 + tx];
  }
  __syncthreads();
#pragma unroll
  for (int j = 0; j < 4; ++j) {
    int c = ty + j * 8;
    outE[(long)(c0 + c) * R + r0 + tx] = (bf16_t)t[tx][c];
  }
}

// ---------------- GEMM kernels ----------------

__device__ __forceinline__ void async_cp16(const bf16_t* g, bf16_t* l) {
  __builtin_amdgcn_global_load_lds(
      (const __attribute__((address_space(1))) unsigned int*)(g),
      (__attribute__((address_space(3))) unsigned int*)(l), 16, 0, 0);
}

// h = silu(X @ W1) * (X @ W3) for one expert slab.
// X: [T][K] bf16 row-major; W1t/W3t: [N][K] bf16 (transposed weights); Hout: [T][N] bf16.
// K = D_ (2048), N = HDIM (1024).
__global__ __launch_bounds__(256, 2) void gemm1_silu(
    const bf16_t* __restrict__ X, const bf16_t* __restrict__ W1t,
    const bf16_t* __restrict__ W3t, bf16_t* __restrict__ Hout,
    long sx, long sw, long sh) {
  const int K   = D_;
  const int NLD = HDIM;
  const bf16_t* A  = X   + (long)blockIdx.z * sx;
  const bf16_t* B1 = W1t + (long)blockIdx.z * sw;
  const bf16_t* B3 = W3t + (long)blockIdx.z * sw;
  bf16_t* HO = Hout + (long)blockIdx.z * sh;

  const int m0 = blockIdx.y * 128;
  const int n0 = blockIdx.x * 128;

  __shared__ bf16_t As[128 * 32];
  __shared__ bf16_t B1s[128 * 32];
  __shared__ bf16_t B3s[128 * 32];

  const int tid  = threadIdx.x;
  const int lane = tid & 63;
  const int wave = tid >> 6;
  const int wm   = (wave >> 1) * 64;
  const int wn   = (wave & 1) * 64;
  const int quad = lane >> 4;
  const int l16  = lane & 15;

  floatx4 acc1[4][4] = {};
  floatx4 acc3[4][4] = {};

  const int srow = tid >> 2;        // 0..63
  const int scol = (tid & 3) * 8;   // 0,8,16,24 (bf16 elems; 16B chunks)

  for (int k0 = 0; k0 < K; k0 += 32) {
    __syncthreads();
#pragma unroll
    for (int r = 0; r < 2; ++r) {
      const int row = r * 64 + srow;
      async_cp16(A  + (long)(m0 + row) * K + k0 + scol, As  + row * 32 + scol);
      async_cp16(B1 + (long)(n0 + row) * K + k0 + scol, B1s + row * 32 + scol);
      async_cp16(B3 + (long)(n0 + row) * K + k0 + scol, B3s + row * 32 + scol);
    }
    __syncthreads();

    bf16x8 af[4], b1f[4], b3f[4];
#pragma unroll
    for (int i = 0; i < 4; ++i)
      af[i] = *(const bf16x8*)(As + (wm + i * 16 + l16) * 32 + quad * 8);
#pragma unroll
    for (int i = 0; i < 4; ++i)
      b1f[i] = *(const bf16x8*)(B1s + (wn + i * 16 + l16) * 32 + quad * 8);
#pragma unroll
    for (int i = 0; i < 4; ++i)
      b3f[i] = *(const bf16x8*)(B3s + (wn + i * 16 + l16) * 32 + quad * 8);

#pragma unroll
    for (int i = 0; i < 4; ++i)
#pragma unroll
      for (int n = 0; n < 4; ++n) {
        acc1[i][n] = __builtin_amdgcn_mfma_f32_16x16x32_bf16(af[i], b1f[n], acc1[i][n], 0, 0, 0);
        acc3[i][n] = __builtin_amdgcn_mfma_f32_16x16x32_bf16(af[i], b3f[n], acc3[i][n], 0, 0, 0);
      }
  }

  // epilogue: silu(g)*u -> bf16.  C/D layout: col=lane&15, row=quad*4+reg (m89-verified)
#pragma unroll
  for (int i = 0; i < 4; ++i)
#pragma unroll
    for (int n = 0; n < 4; ++n) {
      const int col = n0 + wn + n * 16 + l16;
#pragma unroll
      for (int r = 0; r < 4; ++r) {
        const int row = m0 + wm + i * 16 + quad * 4 + r;
        float g = acc1[i][n][r];
        float u = acc3[i][n][r];
        float s = g / (1.0f + __expf(-g));
        HO[(long)row * NLD + col] = (bf16_t)(s * u);
      }
    }
}

// Out = Hin @ W2 for one expert slab.
// Hin: [T][K] bf16 (K=HDIM=1024); W2t: [N][K] bf16 (N=D_=2048); Out: [T][N] fp32.
__global__ __launch_bounds__(256, 2) void gemm2(
    const bf16_t* __restrict__ Hin, const bf16_t* __restrict__ W2t,
    float* __restrict__ Out, long sh, long sw, long so) {
  const int K   = HDIM;
  const int NLD = D_;
  const bf16_t* A = Hin + (long)blockIdx.z * sh;
  const bf16_t* B = W2t + (long)blockIdx.z * sw;
  float* C = Out + (long)blockIdx.z * so;

  const int m0 = blockIdx.y * 128;
  const int n0 = blockIdx.x * 128;

  __shared__ bf16_t As[128 * 32];
  __shared__ bf16_t Bs[128 * 32];

  const int tid  = threadIdx.x;
  const int lane = tid & 63;
  const int wave = tid >> 6;
  const int wm   = (wave >> 1) * 64;
  const int wn   = (wave & 1) * 64;
  const int quad = lane >> 4;
  const int l16  = lane & 15;

  floatx4 acc[4][4] = {};

  const int srow = tid >> 2;
  const int scol = (tid & 3) * 8;

  for (int k0 = 0; k0 < K; k0 += 32) {
    __syncthreads();
#pragma unroll
    for (int r = 0; r < 2; ++r) {
      const int row = r * 64 + srow;
      async_cp16(A + (long)(m0 + row) * K + k0 + scol, As + row * 32 + scol);
      async_cp16(B + (long)(n0 + row) * K + k0 + scol, Bs + row * 32 + scol);
    }
    __syncthreads();

    bf16x8 af[4], bf[4];
#pragma unroll
    for (int i = 0; i < 4; ++i)
      af[i] = *(const bf16x8*)(As + (wm + i * 16 + l16) * 32 + quad * 8);
#pragma unroll
    for (int i = 0; i < 4; ++i)
      bf[i] = *(const bf16x8*)(Bs + (wn + i * 16 + l16) * 32 + quad * 8);

#pragma unroll
    for (int i = 0; i < 4; ++i)
#pragma unroll
      for (int n = 0; n < 4; ++n)
        acc[i][n] = __builtin_amdgcn_mfma_f32_16x16x32_bf16(af[i], bf[n], acc[i][n], 0, 0, 0);
  }

#pragma unroll
  for (int i = 0; i < 4; ++i)
#pragma unroll
    for (int n = 0; n < 4; ++n) {
      const int col = n0 + wn + n * 16 + l16;
#pragma unroll
      for (int r = 0; r < 4; ++r) {
        const int row = m0 + wm + i * 16 + quad * 4 + r;
        C[(long)row * NLD + col] = acc[i][n][r];
      }
    }
}

// ---------------- launcher ----------------

extern "C" void kernel_launch(void* const* d_in, const int* in_sizes, int n_in,
                              void* d_out, int out_size, void* d_ws, size_t ws_size,
                              hipStream_t stream) {
  const float* x  = (const float*)d_in[0];
  const float* w1 = (const float*)d_in[1];
  const float* w2 = (const float*)d_in[2];
  const float* w3 = (const float*)d_in[3];
  float* out = (float*)d_out;

  // bf16 x lives in the first 128 MB of d_out (d_out is 256 MB fp32; validated only
  // after the launch completes, and GEMM2's writes happen after all xb reads).
  bf16_t* xb = (bf16_t*)d_out;
  char* ws = (char*)d_ws;
  const long MB = 1024L * 1024L;

  {
    long n4 = (long)E_ * T_ * D_ / 4;
    cvt_f32_bf16<<<dim3((unsigned)((n4 + 255) / 256)), dim3(256), 0, stream>>>(x, xb, n4);
  }

  const long sWfull = (long)D_ * HDIM;  // per-expert weight elems (all three weights)
  if (ws_size >= (size_t)(160 * MB)) {
    // full-batch path
    bf16_t* w1t = (bf16_t*)(ws + 0 * MB);
    bf16_t* w3t = (bf16_t*)(ws + 32 * MB);
    bf16_t* w2t = (bf16_t*)(ws + 64 * MB);
    bf16_t* hbuf = (bf16_t*)(ws + 96 * MB);

    transpose_cvt<<<dim3(HDIM / 32, D_ / 32, E_), 256, 0, stream>>>(w1, w1t, D_, HDIM, sWfull, sWfull);
    transpose_cvt<<<dim3(HDIM / 32, D_ / 32, E_), 256, 0, stream>>>(w3, w3t, D_, HDIM, sWfull, sWfull);
    transpose_cvt<<<dim3(D_ / 32, HDIM / 32, E_), 256, 0, stream>>>(w2, w2t, HDIM, D_, sWfull, sWfull);

    gemm1_silu<<<dim3(HDIM / 128, T_ / 128, E_), 256, 0, stream>>>(
        xb, w1t, w3t, hbuf, (long)T_ * D_, sWfull, (long)T_ * HDIM);
    gemm2<<<dim3(D_ / 128, T_ / 128, E_), 256, 0, stream>>>(
        hbuf, w2t, out, (long)T_ * HDIM, sWfull, (long)T_ * D_);
  } else {
    // chunked per-expert path (needs only 20 MB of ws). Reverse expert order so that
    // gemm2(e)'s fp32 writes into d_out (clobbering xb[2e],xb[2e+1]) only touch
    // xb slabs whose gemm1 already ran.
    bf16_t* w1t = (bf16_t*)(ws + 0 * MB);
    bf16_t* w3t = (bf16_t*)(ws + 4 * MB);
    bf16_t* w2t = (bf16_t*)(ws + 8 * MB);
    bf16_t* hbuf = (bf16_t*)(ws + 12 * MB);
    for (int e = E_ - 1; e >= 0; --e) {
      const float* w1e = w1 + (long)e * sWfull;
      const float* w3e = w3 + (long)e * sWfull;
      const float* w2e = w2 + (long)e * sWfull;
      transpose_cvt<<<dim3(HDIM / 32, D_ / 32, 1), 256, 0, stream>>>(w1e, w1t, D_, HDIM, 0, 0);
      transpose_cvt<<<dim3(HDIM / 32, D_ / 32, 1), 256, 0, stream>>>(w3e, w3t, D_, HDIM, 0, 0);
      transpose_cvt<<<dim3(D_ / 32, HDIM / 32, 1), 256, 0, stream>>>(w2e, w2t, HDIM, D_, 0, 0);
      gemm1_silu<<<dim3(HDIM / 128, T_ / 128, 1), 256, 0, stream>>>(
          xb + (long)e * T_ * D_, w1t, w3t, hbuf, 0, 0, 0);
      gemm2<<<dim3(D_ / 128, T_ / 128, 1), 256, 0, stream>>>(
          hbuf, w2t, out + (long)e * T_ * D_, 0, 0, 0);
    }
  }
}